// Round 1
// baseline (352.187 us; speedup 1.0000x reference)
//
#include <hip/hip_runtime.h>
#include <hip/hip_bf16.h>

#define Bq 2
#define Tt 2048
#define Cc 2048
#define Hh 16
#define Dd 128
#define Gg 4

using bf16 = __hip_bfloat16;
typedef __attribute__((ext_vector_type(8))) short short8;
typedef __attribute__((ext_vector_type(4))) float f32x4;

__device__ __forceinline__ void gload_lds16(const void* g, void* l) {
    __builtin_amdgcn_global_load_lds(
        (const __attribute__((address_space(1))) unsigned int*)g,
        (__attribute__((address_space(3))) unsigned int*)l, 16, 0, 0);
}

// ---------------- cast x (f32 -> bf16), 4 elems/thread ----------------
__global__ void k_cast_bf16(const float* __restrict__ in, bf16* __restrict__ out, int n4) {
    int i = blockIdx.x * blockDim.x + threadIdx.x;
    if (i >= n4) return;
    float4 v = ((const float4*)in)[i];
    union { bf16 h[4]; uint2 u; } u;
    u.h[0] = __float2bfloat16(v.x);
    u.h[1] = __float2bfloat16(v.y);
    u.h[2] = __float2bfloat16(v.z);
    u.h[3] = __float2bfloat16(v.w);
    ((uint2*)out)[i] = u.u;
}

// ---------------- cast + transpose: in[rows][cols] f32 -> out[cols][ostride] bf16 ----------------
__global__ void k_cast_transpose(const float* __restrict__ in, bf16* __restrict__ out,
                                 int rows, int cols, int ostride) {
    __shared__ float tile[32][33];
    int c0 = blockIdx.x * 32, r0 = blockIdx.y * 32;
    int tx = threadIdx.x, ty = threadIdx.y;  // block (32,8)
    #pragma unroll
    for (int k = 0; k < 4; ++k)
        tile[ty + 8*k][tx] = in[(size_t)(r0 + ty + 8*k) * cols + c0 + tx];
    __syncthreads();
    #pragma unroll
    for (int k = 0; k < 4; ++k)
        out[(size_t)(c0 + ty + 8*k) * ostride + r0 + tx] = __float2bfloat16(tile[tx][ty + 8*k]);
}

// ---------------- GEMM: C[M][N] = A[M][K] @ Bt[N][K]^T, bf16 in, f32 acc ----------------
// 128x128 tile, BK=64, 4 waves (2x2), 16x16x32 MFMA, global_load_lds w/ source-swizzle.
template<int OUTF32>
__global__ __launch_bounds__(256)
void k_gemm_bt(const bf16* __restrict__ A, const bf16* __restrict__ Bt,
               void* __restrict__ C, int M, int N, int K) {
    __shared__ __align__(16) bf16 As[128 * 64];
    __shared__ __align__(16) bf16 Bs[128 * 64];
    const int lane = threadIdx.x & 63;
    const int wave = threadIdx.x >> 6;
    const int row0 = blockIdx.y * 128;
    const int col0 = blockIdx.x * 128;
    const int wm = wave >> 1, wn = wave & 1;
    f32x4 acc[4][4] = {};

    const int srow = lane >> 3;                     // row within 8-row call group
    const int schunk = ((lane & 7) ^ srow) * 8;     // pre-swizzled source chunk (elems)

    for (int k0 = 0; k0 < K; k0 += 64) {
        #pragma unroll
        for (int j = 0; j < 4; ++j) {
            const int c = j * 4 + wave;             // call 0..15, 8 rows each
            const int rt = c * 8 + srow;
            gload_lds16(A  + (size_t)(row0 + rt) * K + k0 + schunk, As + c * 512);
            gload_lds16(Bt + (size_t)(col0 + rt) * K + k0 + schunk, Bs + c * 512);
        }
        __syncthreads();
        #pragma unroll
        for (int kk = 0; kk < 2; ++kk) {
            short8 af[4], bfr[4];
            #pragma unroll
            for (int i = 0; i < 4; ++i) {
                const int ra = wm * 64 + i * 16 + (lane & 15);
                af[i] = *(const short8*)((const char*)As + ra * 128 +
                        ((kk * 64 + (lane >> 4) * 16) ^ ((ra & 7) << 4)));
                const int rb = wn * 64 + i * 16 + (lane & 15);
                bfr[i] = *(const short8*)((const char*)Bs + rb * 128 +
                        ((kk * 64 + (lane >> 4) * 16) ^ ((rb & 7) << 4)));
            }
            #pragma unroll
            for (int i = 0; i < 4; ++i)
                #pragma unroll
                for (int j = 0; j < 4; ++j)
                    acc[i][j] = __builtin_amdgcn_mfma_f32_16x16x32_bf16(af[i], bfr[j], acc[i][j], 0, 0, 0);
        }
        __syncthreads();
    }

    const int crow0 = row0 + wm * 64 + (lane >> 4) * 4;
    const int ccol0 = col0 + wn * 64 + (lane & 15);
    #pragma unroll
    for (int i = 0; i < 4; ++i)
        #pragma unroll
        for (int j = 0; j < 4; ++j)
            #pragma unroll
            for (int r = 0; r < 4; ++r) {
                const size_t idx = (size_t)(crow0 + i * 16 + r) * N + ccol0 + j * 16;
                const float v = acc[i][j][r];
                if (OUTF32) ((float*)C)[idx] = v;
                else        ((bf16*)C)[idx] = __float2bfloat16(v);
            }
}

// ---------------- RMSNorm + RoPE + scatter to per-head layouts ----------------
// QKV[bt][3072]: cols 0..2047 Q(h*128+d), 2048..2559 K(g*128+d), 2560..3071 V.
__global__ void k_qkv_post(const bf16* __restrict__ QKV,
                           const float* __restrict__ cosT, const float* __restrict__ sinT,
                           const float* __restrict__ qs, const float* __restrict__ ks,
                           bf16* __restrict__ Qr, bf16* __restrict__ Kr, bf16* __restrict__ Vr) {
    const int bt = blockIdx.x;
    const int b = bt >> 11;
    const int t = bt & 2047;
    const int lane = threadIdx.x & 63;
    const int wave = threadIdx.x >> 6;
    const float c1 = cosT[t * 128 + lane],      c2 = cosT[t * 128 + 64 + lane];
    const float s1 = sinT[t * 128 + lane],      s2 = sinT[t * 128 + 64 + lane];
    const float qs1 = qs[lane], qs2 = qs[lane + 64];
    const float ks1 = ks[lane], ks2 = ks[lane + 64];
    const bf16* rowb = QKV + (size_t)bt * 3072;
    for (int rr = wave; rr < 24; rr += 4) {
        const bf16* src = rowb + rr * 128;
        const float x1 = __bfloat162float(src[lane]);
        const float x2 = __bfloat162float(src[lane + 64]);
        bf16* dst;
        if (rr < 16)      dst = Qr + ((size_t)(b * Hh + rr) * Tt + t) * 128;
        else if (rr < 20) dst = Kr + ((size_t)(b * Gg + (rr - 16)) * Tt + t) * 128;
        else              dst = Vr + ((size_t)(b * Gg + (rr - 20)) * Tt + t) * 128;
        if (rr < 20) {
            float ssum = x1 * x1 + x2 * x2;
            #pragma unroll
            for (int o = 32; o > 0; o >>= 1) ssum += __shfl_xor(ssum, o);
            const float inv = rsqrtf(ssum * (1.0f / 128.0f) + 1e-6f);
            const float sc1 = (rr < 16) ? qs1 : ks1;
            const float sc2 = (rr < 16) ? qs2 : ks2;
            const float y1 = x1 * inv * sc1;
            const float y2 = x2 * inv * sc2;
            dst[lane]      = __float2bfloat16(y1 * c1 - y2 * s1);
            dst[lane + 64] = __float2bfloat16(y2 * c2 + y1 * s2);
        } else {
            dst[lane]      = src[lane];
            dst[lane + 64] = src[lane + 64];
        }
    }
}

// ---------------- causal flash attention, GQA ----------------
// grid (T/64, B*H), 4 waves x 16 q-rows. K LDS swizzled; V staged transposed; P via per-wave LDS.
__global__ __launch_bounds__(256)
void k_attn(const bf16* __restrict__ Qr, const bf16* __restrict__ Kr, const bf16* __restrict__ Vr,
            bf16* __restrict__ AO) {
    __shared__ __align__(16) bf16 Ksm[64 * 128];
    __shared__ __align__(16) bf16 Vsm[128 * 64];
    __shared__ __align__(16) bf16 Psm[4][16 * 64];
    const int qt = blockIdx.x;
    const int bh = blockIdx.y;
    const int b = bh >> 4;
    const int h = bh & 15;
    const int g = h >> 2;
    const int tid = threadIdx.x;
    const int lane = tid & 63;
    const int wave = tid >> 6;

    const bf16* Qbase = Qr + ((size_t)(b * Hh + h) * Tt + qt * 64) * 128;
    const bf16* Kbase = Kr + (size_t)(b * Gg + g) * Tt * 128;
    const bf16* Vbase = Vr + (size_t)(b * Gg + g) * Tt * 128;

    short8 qf[4];
    #pragma unroll
    for (int kk = 0; kk < 4; ++kk)
        qf[kk] = *(const short8*)(Qbase + (size_t)(wave * 16 + (lane & 15)) * 128 + kk * 32 + (lane >> 4) * 8);

    float m_run[4], l_run[4];
    f32x4 oacc[8];
    #pragma unroll
    for (int r = 0; r < 4; ++r) { m_run[r] = -1e30f; l_run[r] = 0.f; }
    #pragma unroll
    for (int j = 0; j < 8; ++j) oacc[j] = (f32x4){0.f, 0.f, 0.f, 0.f};

    const int ntiles = qt + 1;
    const int vk = tid & 63;
    const int vd0 = tid >> 6;

    for (int tk = 0; tk < ntiles; ++tk) {
        const int k0 = tk * 64;
        #pragma unroll
        for (int j = 0; j < 4; ++j) {                 // K tile: 16 calls x 4 rows(256B)
            const int c = j * 4 + wave;
            const int rt = c * 4 + (lane >> 4);
            const int chunk = (lane & 15) ^ (rt & 7);
            gload_lds16(Kbase + (size_t)(k0 + rt) * 128 + chunk * 8, Ksm + c * 512);
        }
        #pragma unroll
        for (int j = 0; j < 4; ++j) {                 // V transposed into Vsm[d][k]
            const int dc = vd0 + j * 4;
            short8 v = *(const short8*)(Vbase + (size_t)(k0 + vk) * 128 + dc * 8);
            #pragma unroll
            for (int e = 0; e < 8; ++e) {
                const int d = dc * 8 + e;
                *(bf16*)((char*)Vsm + ((d * 128 + vk * 2) ^ ((d & 7) << 4))) = ((bf16*)&v)[e];
            }
        }
        __syncthreads();

        f32x4 s[4];
        #pragma unroll
        for (int nt = 0; nt < 4; ++nt) {
            s[nt] = (f32x4){0.f, 0.f, 0.f, 0.f};
            #pragma unroll
            for (int kk = 0; kk < 4; ++kk) {
                const int rk = nt * 16 + (lane & 15);
                short8 kf = *(const short8*)((const char*)Ksm + rk * 256 +
                            ((kk * 64 + (lane >> 4) * 16) ^ ((rk & 7) << 4)));
                s[nt] = __builtin_amdgcn_mfma_f32_16x16x32_bf16(qf[kk], kf, s[nt], 0, 0, 0);
            }
        }
        const int qrow = qt * 64 + wave * 16 + (lane >> 4) * 4;
        #pragma unroll
        for (int nt = 0; nt < 4; ++nt) {
            const int kcol = k0 + nt * 16 + (lane & 15);
            #pragma unroll
            for (int r = 0; r < 4; ++r) {
                const float v = s[nt][r] * 0.08838834764831845f;
                s[nt][r] = (kcol > qrow + r) ? -1e30f : v;
            }
        }
        float tm[4];
        #pragma unroll
        for (int r = 0; r < 4; ++r)
            tm[r] = fmaxf(fmaxf(s[0][r], s[1][r]), fmaxf(s[2][r], s[3][r]));
        #pragma unroll
        for (int o = 1; o < 16; o <<= 1)
            #pragma unroll
            for (int r = 0; r < 4; ++r) tm[r] = fmaxf(tm[r], __shfl_xor(tm[r], o));
        float fsc[4], ts[4];
        #pragma unroll
        for (int r = 0; r < 4; ++r) {
            const float mn = fmaxf(m_run[r], tm[r]);
            fsc[r] = __expf(m_run[r] - mn);
            m_run[r] = mn;
            l_run[r] *= fsc[r];
            ts[r] = 0.f;
        }
        #pragma unroll
        for (int j = 0; j < 8; ++j)
            #pragma unroll
            for (int r = 0; r < 4; ++r) oacc[j][r] *= fsc[r];
        #pragma unroll
        for (int nt = 0; nt < 4; ++nt)
            #pragma unroll
            for (int r = 0; r < 4; ++r) {
                const float p = __expf(s[nt][r] - m_run[r]);
                ts[r] += p;
                s[nt][r] = p;
            }
        #pragma unroll
        for (int o = 1; o < 16; o <<= 1)
            #pragma unroll
            for (int r = 0; r < 4; ++r) ts[r] += __shfl_xor(ts[r], o);
        #pragma unroll
        for (int r = 0; r < 4; ++r) l_run[r] += ts[r];
        #pragma unroll
        for (int nt = 0; nt < 4; ++nt)
            #pragma unroll
            for (int r = 0; r < 4; ++r) {
                const int prow = (lane >> 4) * 4 + r;
                const int pcol = nt * 16 + (lane & 15);
                *(bf16*)((char*)Psm[wave] + ((prow * 128 + pcol * 2) ^ ((prow & 7) << 4))) =
                    __float2bfloat16(s[nt][r]);
            }
        #pragma unroll
        for (int kk = 0; kk < 2; ++kk) {
            const int pr = lane & 15;
            short8 pf = *(const short8*)((const char*)Psm[wave] + pr * 128 +
                        ((kk * 64 + (lane >> 4) * 16) ^ ((pr & 7) << 4)));
            #pragma unroll
            for (int j = 0; j < 8; ++j) {
                const int dd = j * 16 + (lane & 15);
                short8 vf = *(const short8*)((const char*)Vsm + dd * 128 +
                            ((kk * 64 + (lane >> 4) * 16) ^ ((dd & 7) << 4)));
                oacc[j] = __builtin_amdgcn_mfma_f32_16x16x32_bf16(pf, vf, oacc[j], 0, 0, 0);
            }
        }
        __syncthreads();
    }

    #pragma unroll
    for (int r = 0; r < 4; ++r) {
        const float inv = 1.0f / l_run[r];
        const int qrow = qt * 64 + wave * 16 + (lane >> 4) * 4 + r;
        bf16* dst = AO + (size_t)(b * Tt + qrow) * 2048 + h * 128 + (lane & 15);
        #pragma unroll
        for (int j = 0; j < 8; ++j)
            dst[j * 16] = __float2bfloat16(oacc[j][r] * inv);
    }
}

extern "C" void kernel_launch(void* const* d_in, const int* in_sizes, int n_in,
                              void* d_out, int out_size, void* d_ws, size_t ws_size,
                              hipStream_t stream) {
    const float* x    = (const float*)d_in[0];
    const float* cosT = (const float*)d_in[2];
    const float* sinT = (const float*)d_in[3];
    const float* Wq   = (const float*)d_in[4];
    const float* Wk   = (const float*)d_in[5];
    const float* Wv   = (const float*)d_in[6];
    const float* Wo   = (const float*)d_in[7];
    const float* qs   = (const float*)d_in[8];
    const float* ks   = (const float*)d_in[9];

    char* ws = (char*)d_ws;
    bf16* xb   = (bf16*)(ws);                    // 16.78 MB
    bf16* Wcat = (bf16*)(ws + 16777216);         // [3072][2048] 12.58 MB
    bf16* Wot  = (bf16*)(ws + 29360128);         // [2048][2048] 8.39 MB
    bf16* QKV  = (bf16*)(ws + 37748736);         // [4096][3072] 25.17 MB
    bf16* Qr   = (bf16*)(ws + 62914560);         // [B][H][T][D] 16.78 MB
    bf16* Kr   = (bf16*)(ws + 79691776);         // [B][G][T][D] 4.19 MB
    bf16* Vr   = (bf16*)(ws + 83886080);         // [B][G][T][D] 4.19 MB
    bf16* AO   = (bf16*)(ws + 88080384);         // [B*T][H*D]  16.78 MB

    k_cast_bf16<<<8192, 256, 0, stream>>>(x, xb, 2097152);
    dim3 tb(32, 8);
    k_cast_transpose<<<dim3(64, 64), tb, 0, stream>>>(Wq, Wcat, 2048, 2048, 2048);
    k_cast_transpose<<<dim3(16, 64), tb, 0, stream>>>(Wk, Wcat + (size_t)2048 * 2048, 2048, 512, 2048);
    k_cast_transpose<<<dim3(16, 64), tb, 0, stream>>>(Wv, Wcat + (size_t)2560 * 2048, 2048, 512, 2048);
    k_cast_transpose<<<dim3(64, 64), tb, 0, stream>>>(Wo, Wot, 2048, 2048, 2048);

    k_gemm_bt<0><<<dim3(24, 32), 256, 0, stream>>>(xb, Wcat, QKV, 4096, 3072, 2048);
    k_qkv_post<<<4096, 256, 0, stream>>>(QKV, cosT, sinT, qs, ks, Qr, Kr, Vr);
    k_attn<<<dim3(32, 32), 256, 0, stream>>>(Qr, Kr, Vr, AO);
    k_gemm_bt<1><<<dim3(16, 32), 256, 0, stream>>>(AO, Wot, d_out, 4096, 2048, 2048);
}

// Round 2
// 228.690 us; speedup vs baseline: 1.5400x; 1.5400x over previous
//
#include <hip/hip_runtime.h>
#include <hip/hip_bf16.h>

#define Bq 2
#define Tt 2048
#define Cc 2048
#define Hh 16
#define Dd 128
#define Gg 4

using bf16 = __hip_bfloat16;
typedef __attribute__((ext_vector_type(8))) short short8;
typedef __attribute__((ext_vector_type(4))) float f32x4;

__device__ __forceinline__ void gload_lds16(const void* g, void* l) {
    __builtin_amdgcn_global_load_lds(
        (const __attribute__((address_space(1))) unsigned int*)g,
        (__attribute__((address_space(3))) unsigned int*)l, 16, 0, 0);
}

// ---------------- cast x (f32 -> bf16), 4 elems/thread ----------------
__global__ void k_cast_bf16(const float* __restrict__ in, bf16* __restrict__ out, int n4) {
    int i = blockIdx.x * blockDim.x + threadIdx.x;
    if (i >= n4) return;
    float4 v = ((const float4*)in)[i];
    union { bf16 h[4]; uint2 u; } u;
    u.h[0] = __float2bfloat16(v.x);
    u.h[1] = __float2bfloat16(v.y);
    u.h[2] = __float2bfloat16(v.z);
    u.h[3] = __float2bfloat16(v.w);
    ((uint2*)out)[i] = u.u;
}

// ---------------- cast + transpose: in[rows][cols] f32 -> out[cols][ostride] bf16 ----------------
__global__ void k_cast_transpose(const float* __restrict__ in, bf16* __restrict__ out,
                                 int rows, int cols, int ostride) {
    __shared__ float tile[32][33];
    int c0 = blockIdx.x * 32, r0 = blockIdx.y * 32;
    int tx = threadIdx.x, ty = threadIdx.y;  // block (32,8)
    #pragma unroll
    for (int k = 0; k < 4; ++k)
        tile[ty + 8*k][tx] = in[(size_t)(r0 + ty + 8*k) * cols + c0 + tx];
    __syncthreads();
    #pragma unroll
    for (int k = 0; k < 4; ++k)
        out[(size_t)(c0 + ty + 8*k) * ostride + r0 + tx] = __float2bfloat16(tile[tx][ty + 8*k]);
}

// ---------------- bf16 transpose of V columns of QKV -> Vt[b][g][d][t] ----------------
// 64x64 tiles. block (64,8). grid (D/64, T/64, B*G)
__global__ void k_vt(const bf16* __restrict__ QKV, bf16* __restrict__ Vt) {
    __shared__ bf16 tile[64][65];
    const int d0 = blockIdx.x * 64, t0 = blockIdx.y * 64;
    const int bg = blockIdx.z;
    const int b = bg >> 2, g = bg & 3;
    const int tx = threadIdx.x, ty = threadIdx.y;
    const bf16* src = QKV + (size_t)(b * Tt) * 3072 + 2560 + g * 128;
    #pragma unroll
    for (int k = 0; k < 8; ++k)
        tile[ty + 8*k][tx] = src[(size_t)(t0 + ty + 8*k) * 3072 + d0 + tx];
    __syncthreads();
    bf16* dst = Vt + (size_t)bg * Dd * Tt;
    #pragma unroll
    for (int k = 0; k < 8; ++k)
        dst[(size_t)(d0 + ty + 8*k) * Tt + t0 + tx] = tile[tx][ty + 8*k];
}

// ---------------- GEMM: C[M][N] = A[M][K] @ Bt[N][K]^T, bf16 in, f32 acc ----------------
template<int OUTF32>
__global__ __launch_bounds__(256)
void k_gemm_bt(const bf16* __restrict__ A, const bf16* __restrict__ Bt,
               void* __restrict__ C, int M, int N, int K) {
    __shared__ __align__(16) bf16 As[128 * 64];
    __shared__ __align__(16) bf16 Bs[128 * 64];
    const int lane = threadIdx.x & 63;
    const int wave = threadIdx.x >> 6;
    const int row0 = blockIdx.y * 128;
    const int col0 = blockIdx.x * 128;
    const int wm = wave >> 1, wn = wave & 1;
    f32x4 acc[4][4] = {};

    const int srow = lane >> 3;
    const int schunk = ((lane & 7) ^ srow) * 8;

    for (int k0 = 0; k0 < K; k0 += 64) {
        #pragma unroll
        for (int j = 0; j < 4; ++j) {
            const int c = j * 4 + wave;
            const int rt = c * 8 + srow;
            gload_lds16(A  + (size_t)(row0 + rt) * K + k0 + schunk, As + c * 512);
            gload_lds16(Bt + (size_t)(col0 + rt) * K + k0 + schunk, Bs + c * 512);
        }
        __syncthreads();
        #pragma unroll
        for (int kk = 0; kk < 2; ++kk) {
            short8 af[4], bfr[4];
            #pragma unroll
            for (int i = 0; i < 4; ++i) {
                const int ra = wm * 64 + i * 16 + (lane & 15);
                af[i] = *(const short8*)((const char*)As + ra * 128 +
                        ((kk * 64 + (lane >> 4) * 16) ^ ((ra & 7) << 4)));
                const int rb = wn * 64 + i * 16 + (lane & 15);
                bfr[i] = *(const short8*)((const char*)Bs + rb * 128 +
                        ((kk * 64 + (lane >> 4) * 16) ^ ((rb & 7) << 4)));
            }
            __builtin_amdgcn_s_setprio(1);
            #pragma unroll
            for (int i = 0; i < 4; ++i)
                #pragma unroll
                for (int j = 0; j < 4; ++j)
                    acc[i][j] = __builtin_amdgcn_mfma_f32_16x16x32_bf16(af[i], bfr[j], acc[i][j], 0, 0, 0);
            __builtin_amdgcn_s_setprio(0);
        }
        __syncthreads();
    }

    const int crow0 = row0 + wm * 64 + (lane >> 4) * 4;
    const int ccol0 = col0 + wn * 64 + (lane & 15);
    #pragma unroll
    for (int i = 0; i < 4; ++i)
        #pragma unroll
        for (int j = 0; j < 4; ++j)
            #pragma unroll
            for (int r = 0; r < 4; ++r) {
                const size_t idx = (size_t)(crow0 + i * 16 + r) * N + ccol0 + j * 16;
                const float v = acc[i][j][r];
                if (OUTF32) ((float*)C)[idx] = v;
                else        ((bf16*)C)[idx] = __float2bfloat16(v);
            }
}

// ---------------- RMSNorm + RoPE + scatter Q,K to per-head layouts ----------------
__global__ void k_qkv_post(const bf16* __restrict__ QKV,
                           const float* __restrict__ cosT, const float* __restrict__ sinT,
                           const float* __restrict__ qs, const float* __restrict__ ks,
                           bf16* __restrict__ Qr, bf16* __restrict__ Kr) {
    const int bt = blockIdx.x;
    const int b = bt >> 11;
    const int t = bt & 2047;
    const int lane = threadIdx.x & 63;
    const int wave = threadIdx.x >> 6;
    const float c1 = cosT[t * 128 + lane],      c2 = cosT[t * 128 + 64 + lane];
    const float s1 = sinT[t * 128 + lane],      s2 = sinT[t * 128 + 64 + lane];
    const float qs1 = qs[lane], qs2 = qs[lane + 64];
    const float ks1 = ks[lane], ks2 = ks[lane + 64];
    const bf16* rowb = QKV + (size_t)bt * 3072;
    for (int rr = wave; rr < 20; rr += 4) {
        const bf16* src = rowb + rr * 128;
        const float x1 = __bfloat162float(src[lane]);
        const float x2 = __bfloat162float(src[lane + 64]);
        bf16* dst;
        if (rr < 16) dst = Qr + ((size_t)(b * Hh + rr) * Tt + t) * 128;
        else         dst = Kr + ((size_t)(b * Gg + (rr - 16)) * Tt + t) * 128;
        float ssum = x1 * x1 + x2 * x2;
        #pragma unroll
        for (int o = 32; o > 0; o >>= 1) ssum += __shfl_xor(ssum, o);
        const float inv = rsqrtf(ssum * (1.0f / 128.0f) + 1e-6f);
        const float sc1 = (rr < 16) ? qs1 : ks1;
        const float sc2 = (rr < 16) ? qs2 : ks2;
        const float y1 = x1 * inv * sc1;
        const float y2 = x2 * inv * sc2;
        dst[lane]      = __float2bfloat16(y1 * c1 - y2 * s1);
        dst[lane + 64] = __float2bfloat16(y2 * c2 + y1 * s2);
    }
}

// ---------------- causal flash attention, GQA, fold-paired ----------------
// 512 blocks: id&7 = (b,g) -> XCD affinity; each block does q-tiles (p, 31-p): 33 KV-iters.
__global__ __launch_bounds__(256)
void k_attn(const bf16* __restrict__ Qr, const bf16* __restrict__ Kr,
            const bf16* __restrict__ Vt, bf16* __restrict__ AO) {
    __shared__ __align__(16) bf16 Ksm[64 * 128];
    __shared__ __align__(16) bf16 Vsm[128 * 64];
    __shared__ __align__(16) bf16 Psm[4][16 * 64];
    const int id = blockIdx.x;
    const int bg = id & 7;            // one (b,g) per XCD -> K/V L2-resident
    const int wid = id >> 3;          // 0..63
    const int pair = wid & 15;
    const int hg = wid >> 4;          // 0..3
    const int b = bg >> 2, g = bg & 3;
    const int h = g * 4 + hg;
    const int lane = threadIdx.x & 63;
    const int wave = threadIdx.x >> 6;

    const bf16* Kbase = Kr + (size_t)(b * Gg + g) * Tt * Dd;
    const bf16* Vbase = Vt + (size_t)(b * Gg + g) * Dd * Tt;

    for (int pass = 0; pass < 2; ++pass) {
        const int qt = pass ? (31 - pair) : pair;
        const bf16* Qbase = Qr + ((size_t)(b * Hh + h) * Tt + qt * 64) * Dd;

        short8 qf[4];
        #pragma unroll
        for (int kk = 0; kk < 4; ++kk)
            qf[kk] = *(const short8*)(Qbase + (size_t)(wave * 16 + (lane & 15)) * 128 + kk * 32 + (lane >> 4) * 8);

        float m_run[4], l_run[4];
        f32x4 oacc[8];
        #pragma unroll
        for (int r = 0; r < 4; ++r) { m_run[r] = -1e30f; l_run[r] = 0.f; }
        #pragma unroll
        for (int j = 0; j < 8; ++j) oacc[j] = (f32x4){0.f, 0.f, 0.f, 0.f};

        for (int tk = 0; tk <= qt; ++tk) {
            const int k0 = tk * 64;
            #pragma unroll
            for (int j = 0; j < 4; ++j) {             // K tile [64 t][128 d], swizzled src
                const int c = j * 4 + wave;
                const int rt = c * 4 + (lane >> 4);
                const int chunk = (lane & 15) ^ (rt & 7);
                gload_lds16(Kbase + (size_t)(k0 + rt) * 128 + chunk * 8, Ksm + c * 512);
            }
            #pragma unroll
            for (int j = 0; j < 4; ++j) {             // V^T tile [128 d][64 t], swizzled src
                const int c = j * 4 + wave;
                const int rt = c * 8 + (lane >> 3);
                const int chunk = (lane & 7) ^ ((lane >> 3) & 7);
                gload_lds16(Vbase + (size_t)rt * Tt + k0 + chunk * 8, Vsm + c * 512);
            }
            __syncthreads();

            f32x4 s[4];
            #pragma unroll
            for (int nt = 0; nt < 4; ++nt) s[nt] = (f32x4){0.f, 0.f, 0.f, 0.f};
            __builtin_amdgcn_s_setprio(1);
            #pragma unroll
            for (int nt = 0; nt < 4; ++nt) {
                #pragma unroll
                for (int kk = 0; kk < 4; ++kk) {
                    const int rk = nt * 16 + (lane & 15);
                    short8 kf = *(const short8*)((const char*)Ksm + rk * 256 +
                                ((kk * 64 + (lane >> 4) * 16) ^ ((rk & 7) << 4)));
                    s[nt] = __builtin_amdgcn_mfma_f32_16x16x32_bf16(qf[kk], kf, s[nt], 0, 0, 0);
                }
            }
            __builtin_amdgcn_s_setprio(0);

            const int qrow = qt * 64 + wave * 16 + (lane >> 4) * 4;
            #pragma unroll
            for (int nt = 0; nt < 4; ++nt) {
                const int kcol = k0 + nt * 16 + (lane & 15);
                #pragma unroll
                for (int r = 0; r < 4; ++r) {
                    const float v = s[nt][r] * 0.08838834764831845f;
                    s[nt][r] = (kcol > qrow + r) ? -1e30f : v;
                }
            }
            float tm[4];
            #pragma unroll
            for (int r = 0; r < 4; ++r)
                tm[r] = fmaxf(fmaxf(s[0][r], s[1][r]), fmaxf(s[2][r], s[3][r]));
            #pragma unroll
            for (int o = 1; o < 16; o <<= 1)
                #pragma unroll
                for (int r = 0; r < 4; ++r) tm[r] = fmaxf(tm[r], __shfl_xor(tm[r], o));
            float fsc[4], ts[4];
            #pragma unroll
            for (int r = 0; r < 4; ++r) {
                const float mn = fmaxf(m_run[r], tm[r]);
                fsc[r] = __expf(m_run[r] - mn);
                m_run[r] = mn;
                l_run[r] *= fsc[r];
                ts[r] = 0.f;
            }
            #pragma unroll
            for (int j = 0; j < 8; ++j)
                #pragma unroll
                for (int r = 0; r < 4; ++r) oacc[j][r] *= fsc[r];
            #pragma unroll
            for (int nt = 0; nt < 4; ++nt)
                #pragma unroll
                for (int r = 0; r < 4; ++r) {
                    const float p = __expf(s[nt][r] - m_run[r]);
                    ts[r] += p;
                    s[nt][r] = p;
                }
            #pragma unroll
            for (int o = 1; o < 16; o <<= 1)
                #pragma unroll
                for (int r = 0; r < 4; ++r) ts[r] += __shfl_xor(ts[r], o);
            #pragma unroll
            for (int r = 0; r < 4; ++r) l_run[r] += ts[r];

            #pragma unroll
            for (int nt = 0; nt < 4; ++nt)
                #pragma unroll
                for (int r = 0; r < 4; ++r) {
                    const int prow = (lane >> 4) * 4 + r;
                    const int pcol = nt * 16 + (lane & 15);
                    *(bf16*)((char*)Psm[wave] + ((prow * 128 + pcol * 2) ^ ((prow & 7) << 4))) =
                        __float2bfloat16(s[nt][r]);
                }
            #pragma unroll
            for (int kk = 0; kk < 2; ++kk) {
                const int pr = lane & 15;
                short8 pf = *(const short8*)((const char*)Psm[wave] + pr * 128 +
                            ((kk * 64 + (lane >> 4) * 16) ^ ((pr & 7) << 4)));
                __builtin_amdgcn_s_setprio(1);
                #pragma unroll
                for (int j = 0; j < 8; ++j) {
                    const int rb = j * 16 + (lane & 15);
                    short8 vf = *(const short8*)((const char*)Vsm + rb * 128 +
                                ((kk * 64 + (lane >> 4) * 16) ^ ((rb & 7) << 4)));
                    oacc[j] = __builtin_amdgcn_mfma_f32_16x16x32_bf16(pf, vf, oacc[j], 0, 0, 0);
                }
                __builtin_amdgcn_s_setprio(0);
            }
            __syncthreads();
        }

        #pragma unroll
        for (int r = 0; r < 4; ++r) {
            const float inv = 1.0f / l_run[r];
            const int qrow = qt * 64 + wave * 16 + (lane >> 4) * 4 + r;
            bf16* dst = AO + (size_t)(b * Tt + qrow) * 2048 + h * 128 + (lane & 15);
            #pragma unroll
            for (int j = 0; j < 8; ++j)
                dst[j * 16] = __float2bfloat16(oacc[j][r] * inv);
        }
    }
}

extern "C" void kernel_launch(void* const* d_in, const int* in_sizes, int n_in,
                              void* d_out, int out_size, void* d_ws, size_t ws_size,
                              hipStream_t stream) {
    const float* x    = (const float*)d_in[0];
    const float* cosT = (const float*)d_in[2];
    const float* sinT = (const float*)d_in[3];
    const float* Wq   = (const float*)d_in[4];
    const float* Wk   = (const float*)d_in[5];
    const float* Wv   = (const float*)d_in[6];
    const float* Wo   = (const float*)d_in[7];
    const float* qs   = (const float*)d_in[8];
    const float* ks   = (const float*)d_in[9];

    char* ws = (char*)d_ws;
    bf16* xb   = (bf16*)(ws);                    // 16.78 MB
    bf16* Wcat = (bf16*)(ws + 16777216);         // [3072][2048] 12.58 MB
    bf16* Wot  = (bf16*)(ws + 29360128);         // [2048][2048] 8.39 MB
    bf16* QKV  = (bf16*)(ws + 37748736);         // [4096][3072] 25.17 MB
    bf16* Qr   = (bf16*)(ws + 62914560);         // [B][H][T][D] 16.78 MB
    bf16* Kr   = (bf16*)(ws + 79691776);         // [B][G][T][D] 4.19 MB
    bf16* Vtp  = (bf16*)(ws + 83886080);         // [B][G][D][T] 4.19 MB
    bf16* AO   = (bf16*)(ws + 88080384);         // [B*T][H*D]  16.78 MB

    k_cast_bf16<<<8192, 256, 0, stream>>>(x, xb, 2097152);
    dim3 tb(32, 8);
    k_cast_transpose<<<dim3(64, 64), tb, 0, stream>>>(Wq, Wcat, 2048, 2048, 2048);
    k_cast_transpose<<<dim3(16, 64), tb, 0, stream>>>(Wk, Wcat + (size_t)2048 * 2048, 2048, 512, 2048);
    k_cast_transpose<<<dim3(16, 64), tb, 0, stream>>>(Wv, Wcat + (size_t)2560 * 2048, 2048, 512, 2048);
    k_cast_transpose<<<dim3(64, 64), tb, 0, stream>>>(Wo, Wot, 2048, 2048, 2048);

    k_gemm_bt<0><<<dim3(24, 32), 256, 0, stream>>>(xb, Wcat, QKV, 4096, 3072, 2048);
    k_qkv_post<<<4096, 256, 0, stream>>>(QKV, cosT, sinT, qs, ks, Qr, Kr);
    k_vt<<<dim3(2, 32, 8), dim3(64, 8), 0, stream>>>(QKV, Vtp);
    k_attn<<<512, 256, 0, stream>>>(Qr, Kr, Vtp, AO);
    k_gemm_bt<1><<<dim3(16, 32), 256, 0, stream>>>(AO, Wot, d_out, 4096, 2048, 2048);
}

// Round 3
// 225.628 us; speedup vs baseline: 1.5609x; 1.0136x over previous
//
#include <hip/hip_runtime.h>
#include <hip/hip_bf16.h>

#define Bq 2
#define Tt 2048
#define Cc 2048
#define Hh 16
#define Dd 128
#define Gg 4

using bf16 = __hip_bfloat16;
typedef __attribute__((ext_vector_type(8))) short short8;
typedef __attribute__((ext_vector_type(4))) float f32x4;

__device__ __forceinline__ void gload_lds16(const void* g, void* l) {
    __builtin_amdgcn_global_load_lds(
        (const __attribute__((address_space(1))) unsigned int*)g,
        (__attribute__((address_space(3))) unsigned int*)l, 16, 0, 0);
}

// ---------------- cast x (f32 -> bf16), 4 elems/thread ----------------
__global__ void k_cast_bf16(const float* __restrict__ in, bf16* __restrict__ out, int n4) {
    int i = blockIdx.x * blockDim.x + threadIdx.x;
    if (i >= n4) return;
    float4 v = ((const float4*)in)[i];
    union { bf16 h[4]; uint2 u; } u;
    u.h[0] = __float2bfloat16(v.x);
    u.h[1] = __float2bfloat16(v.y);
    u.h[2] = __float2bfloat16(v.z);
    u.h[3] = __float2bfloat16(v.w);
    ((uint2*)out)[i] = u.u;
}

// ---------------- cast + transpose: in[rows][cols] f32 -> out[cols][ostride] bf16 ----------------
__global__ void k_cast_transpose(const float* __restrict__ in, bf16* __restrict__ out,
                                 int rows, int cols, int ostride) {
    __shared__ float tile[32][33];
    int c0 = blockIdx.x * 32, r0 = blockIdx.y * 32;
    int tx = threadIdx.x, ty = threadIdx.y;  // block (32,8)
    #pragma unroll
    for (int k = 0; k < 4; ++k)
        tile[ty + 8*k][tx] = in[(size_t)(r0 + ty + 8*k) * cols + c0 + tx];
    __syncthreads();
    #pragma unroll
    for (int k = 0; k < 4; ++k)
        out[(size_t)(c0 + ty + 8*k) * ostride + r0 + tx] = __float2bfloat16(tile[tx][ty + 8*k]);
}

// ---------------- bf16 transpose of V columns of QKV -> Vt[b][g][d][t] ----------------
__global__ void k_vt(const bf16* __restrict__ QKV, bf16* __restrict__ Vt) {
    __shared__ bf16 tile[64][65];
    const int d0 = blockIdx.x * 64, t0 = blockIdx.y * 64;
    const int bg = blockIdx.z;
    const int b = bg >> 2, g = bg & 3;
    const int tx = threadIdx.x, ty = threadIdx.y;
    const bf16* src = QKV + (size_t)(b * Tt) * 3072 + 2560 + g * 128;
    #pragma unroll
    for (int k = 0; k < 8; ++k)
        tile[ty + 8*k][tx] = src[(size_t)(t0 + ty + 8*k) * 3072 + d0 + tx];
    __syncthreads();
    bf16* dst = Vt + (size_t)bg * Dd * Tt;
    #pragma unroll
    for (int k = 0; k < 8; ++k)
        dst[(size_t)(d0 + ty + 8*k) * Tt + t0 + tx] = tile[tx][ty + 8*k];
}

// ---------------- GEMM: C[M][N] = A[M][K] @ Bt[N][K]^T, bf16 in, f32 acc ----------------
template<int OUTF32>
__global__ __launch_bounds__(256)
void k_gemm_bt(const bf16* __restrict__ A, const bf16* __restrict__ Bt,
               void* __restrict__ C, int M, int N, int K) {
    __shared__ __align__(16) bf16 As[128 * 64];
    __shared__ __align__(16) bf16 Bs[128 * 64];
    const int lane = threadIdx.x & 63;
    const int wave = threadIdx.x >> 6;
    const int row0 = blockIdx.y * 128;
    const int col0 = blockIdx.x * 128;
    const int wm = wave >> 1, wn = wave & 1;
    f32x4 acc[4][4] = {};

    const int srow = lane >> 3;
    const int schunk = ((lane & 7) ^ srow) * 8;

    for (int k0 = 0; k0 < K; k0 += 64) {
        #pragma unroll
        for (int j = 0; j < 4; ++j) {
            const int c = j * 4 + wave;
            const int rt = c * 8 + srow;
            gload_lds16(A  + (size_t)(row0 + rt) * K + k0 + schunk, As + c * 512);
            gload_lds16(Bt + (size_t)(col0 + rt) * K + k0 + schunk, Bs + c * 512);
        }
        __syncthreads();
        #pragma unroll
        for (int kk = 0; kk < 2; ++kk) {
            short8 af[4], bfr[4];
            #pragma unroll
            for (int i = 0; i < 4; ++i) {
                const int ra = wm * 64 + i * 16 + (lane & 15);
                af[i] = *(const short8*)((const char*)As + ra * 128 +
                        ((kk * 64 + (lane >> 4) * 16) ^ ((ra & 7) << 4)));
                const int rb = wn * 64 + i * 16 + (lane & 15);
                bfr[i] = *(const short8*)((const char*)Bs + rb * 128 +
                        ((kk * 64 + (lane >> 4) * 16) ^ ((rb & 7) << 4)));
            }
            __builtin_amdgcn_s_setprio(1);
            #pragma unroll
            for (int i = 0; i < 4; ++i)
                #pragma unroll
                for (int j = 0; j < 4; ++j)
                    acc[i][j] = __builtin_amdgcn_mfma_f32_16x16x32_bf16(af[i], bfr[j], acc[i][j], 0, 0, 0);
            __builtin_amdgcn_s_setprio(0);
        }
        __syncthreads();
    }

    const int crow0 = row0 + wm * 64 + (lane >> 4) * 4;
    const int ccol0 = col0 + wn * 64 + (lane & 15);
    #pragma unroll
    for (int i = 0; i < 4; ++i)
        #pragma unroll
        for (int j = 0; j < 4; ++j)
            #pragma unroll
            for (int r = 0; r < 4; ++r) {
                const size_t idx = (size_t)(crow0 + i * 16 + r) * N + ccol0 + j * 16;
                const float v = acc[i][j][r];
                if (OUTF32) ((float*)C)[idx] = v;
                else        ((bf16*)C)[idx] = __float2bfloat16(v);
            }
}

// ---------------- RMSNorm + RoPE + scatter Q,K; Q pre-scaled by D^-1/2 ----------------
__global__ void k_qkv_post(const bf16* __restrict__ QKV,
                           const float* __restrict__ cosT, const float* __restrict__ sinT,
                           const float* __restrict__ qs, const float* __restrict__ ks,
                           bf16* __restrict__ Qr, bf16* __restrict__ Kr) {
    const int bt = blockIdx.x;
    const int b = bt >> 11;
    const int t = bt & 2047;
    const int lane = threadIdx.x & 63;
    const int wave = threadIdx.x >> 6;
    const float c1 = cosT[t * 128 + lane],      c2 = cosT[t * 128 + 64 + lane];
    const float s1 = sinT[t * 128 + lane],      s2 = sinT[t * 128 + 64 + lane];
    const float qs1 = qs[lane], qs2 = qs[lane + 64];
    const float ks1 = ks[lane], ks2 = ks[lane + 64];
    const bf16* rowb = QKV + (size_t)bt * 3072;
    for (int rr = wave; rr < 20; rr += 4) {
        const bf16* src = rowb + rr * 128;
        const float x1 = __bfloat162float(src[lane]);
        const float x2 = __bfloat162float(src[lane + 64]);
        bf16* dst;
        if (rr < 16) dst = Qr + ((size_t)(b * Hh + rr) * Tt + t) * 128;
        else         dst = Kr + ((size_t)(b * Gg + (rr - 16)) * Tt + t) * 128;
        float ssum = x1 * x1 + x2 * x2;
        #pragma unroll
        for (int o = 32; o > 0; o >>= 1) ssum += __shfl_xor(ssum, o);
        const float inv = rsqrtf(ssum * (1.0f / 128.0f) + 1e-6f);
        const float post = (rr < 16) ? 0.08838834764831845f : 1.0f;  // fold 1/sqrt(D) into Q
        const float sc1 = ((rr < 16) ? qs1 : ks1) * inv;
        const float sc2 = ((rr < 16) ? qs2 : ks2) * inv;
        const float y1 = x1 * sc1;
        const float y2 = x2 * sc2;
        dst[lane]      = __float2bfloat16((y1 * c1 - y2 * s1) * post);
        dst[lane + 64] = __float2bfloat16((y2 * c2 + y1 * s2) * post);
    }
}

// ---------------- causal flash attention, GQA, fold-paired, double-buffered ----------------
__global__ __launch_bounds__(256)
void k_attn(const bf16* __restrict__ Qr, const bf16* __restrict__ Kr,
            const bf16* __restrict__ Vt, bf16* __restrict__ AO) {
    __shared__ __align__(16) bf16 Ksm[2][64 * 128];
    __shared__ __align__(16) bf16 Vsm[2][128 * 64];
    __shared__ __align__(16) bf16 Psm[4][16 * 64];
    const int id = blockIdx.x;
    const int bg = id & 7;            // one (b,g) per XCD -> K/V L2-resident
    const int wid = id >> 3;          // 0..63
    const int pair = wid & 15;
    const int hg = wid >> 4;          // 0..3
    const int b = bg >> 2, g = bg & 3;
    const int h = g * 4 + hg;
    const int lane = threadIdx.x & 63;
    const int wave = threadIdx.x >> 6;

    const bf16* Kbase = Kr + (size_t)(b * Gg + g) * Tt * Dd;
    const bf16* Vbase = Vt + (size_t)(b * Gg + g) * Dd * Tt;

    for (int pass = 0; pass < 2; ++pass) {
        const int qt = pass ? (31 - pair) : pair;
        const bf16* Qbase = Qr + ((size_t)(b * Hh + h) * Tt + qt * 64) * Dd;

        short8 qf[4];
        #pragma unroll
        for (int kk = 0; kk < 4; ++kk)
            qf[kk] = *(const short8*)(Qbase + (size_t)(wave * 16 + (lane & 15)) * 128 + kk * 32 + (lane >> 4) * 8);

        float m_run[4], l_run[4];
        f32x4 oacc[8];
        #pragma unroll
        for (int r = 0; r < 4; ++r) { m_run[r] = -1e30f; l_run[r] = 0.f; }
        #pragma unroll
        for (int j = 0; j < 8; ++j) oacc[j] = (f32x4){0.f, 0.f, 0.f, 0.f};

        // stage tile 0 into buffer 0
        {
            const int k0 = 0;
            #pragma unroll
            for (int j = 0; j < 4; ++j) {
                const int c = j * 4 + wave;
                const int rtk = c * 4 + (lane >> 4);
                const int chk = (lane & 15) ^ (rtk & 7);
                gload_lds16(Kbase + (size_t)(k0 + rtk) * 128 + chk * 8, Ksm[0] + c * 512);
                const int rtv = c * 8 + (lane >> 3);
                const int chv = (lane & 7) ^ ((lane >> 3) & 7);
                gload_lds16(Vbase + (size_t)rtv * Tt + k0 + chv * 8, Vsm[0] + c * 512);
            }
        }

        int cur = 0;
        for (int tk = 0; tk <= qt; ++tk) {
            __syncthreads();   // buf[cur] staged (barrier drains vmcnt)

            if (tk < qt) {     // prefetch next tile into other buffer; hides under compute
                const int k0n = (tk + 1) * 64;
                #pragma unroll
                for (int j = 0; j < 4; ++j) {
                    const int c = j * 4 + wave;
                    const int rtk = c * 4 + (lane >> 4);
                    const int chk = (lane & 15) ^ (rtk & 7);
                    gload_lds16(Kbase + (size_t)(k0n + rtk) * 128 + chk * 8, Ksm[cur ^ 1] + c * 512);
                    const int rtv = c * 8 + (lane >> 3);
                    const int chv = (lane & 7) ^ ((lane >> 3) & 7);
                    gload_lds16(Vbase + (size_t)rtv * Tt + k0n + chv * 8, Vsm[cur ^ 1] + c * 512);
                }
            }

            const bf16* Ks = Ksm[cur];
            const bf16* Vs = Vsm[cur];

            f32x4 s[4];
            #pragma unroll
            for (int nt = 0; nt < 4; ++nt) s[nt] = (f32x4){0.f, 0.f, 0.f, 0.f};
            __builtin_amdgcn_s_setprio(1);
            #pragma unroll
            for (int nt = 0; nt < 4; ++nt) {
                #pragma unroll
                for (int kk = 0; kk < 4; ++kk) {
                    const int rk = nt * 16 + (lane & 15);
                    short8 kf = *(const short8*)((const char*)Ks + rk * 256 +
                                ((kk * 64 + (lane >> 4) * 16) ^ ((rk & 7) << 4)));
                    s[nt] = __builtin_amdgcn_mfma_f32_16x16x32_bf16(qf[kk], kf, s[nt], 0, 0, 0);
                }
            }
            __builtin_amdgcn_s_setprio(0);

            if (tk == qt) {    // mask only the diagonal tile
                const int qrow = qt * 64 + wave * 16 + (lane >> 4) * 4;
                const int k0 = tk * 64;
                #pragma unroll
                for (int nt = 0; nt < 4; ++nt) {
                    const int kcol = k0 + nt * 16 + (lane & 15);
                    #pragma unroll
                    for (int r = 0; r < 4; ++r)
                        if (kcol > qrow + r) s[nt][r] = -1e30f;
                }
            }

            float tm[4];
            #pragma unroll
            for (int r = 0; r < 4; ++r)
                tm[r] = fmaxf(fmaxf(s[0][r], s[1][r]), fmaxf(s[2][r], s[3][r]));
            #pragma unroll
            for (int o = 1; o < 16; o <<= 1)
                #pragma unroll
                for (int r = 0; r < 4; ++r) tm[r] = fmaxf(tm[r], __shfl_xor(tm[r], o));

            // defer-max: only rescale when a row max grew past m_run + 8
            bool ok = true;
            #pragma unroll
            for (int r = 0; r < 4; ++r) ok = ok && (tm[r] <= m_run[r] + 8.0f);
            if (!__all(ok)) {
                float fsc[4];
                #pragma unroll
                for (int r = 0; r < 4; ++r) {
                    const float mn = fmaxf(m_run[r], tm[r]);
                    fsc[r] = __expf(m_run[r] - mn);
                    m_run[r] = mn;
                    l_run[r] *= fsc[r];
                }
                #pragma unroll
                for (int j = 0; j < 8; ++j)
                    #pragma unroll
                    for (int r = 0; r < 4; ++r) oacc[j][r] *= fsc[r];
            }

            float ts[4] = {0.f, 0.f, 0.f, 0.f};
            #pragma unroll
            for (int nt = 0; nt < 4; ++nt)
                #pragma unroll
                for (int r = 0; r < 4; ++r) {
                    const float p = __expf(s[nt][r] - m_run[r]);
                    ts[r] += p;
                    s[nt][r] = p;
                }
            #pragma unroll
            for (int o = 1; o < 16; o <<= 1)
                #pragma unroll
                for (int r = 0; r < 4; ++r) ts[r] += __shfl_xor(ts[r], o);
            #pragma unroll
            for (int r = 0; r < 4; ++r) l_run[r] += ts[r];

            #pragma unroll
            for (int nt = 0; nt < 4; ++nt)
                #pragma unroll
                for (int r = 0; r < 4; ++r) {
                    const int prow = (lane >> 4) * 4 + r;
                    const int pcol = nt * 16 + (lane & 15);
                    *(bf16*)((char*)Psm[wave] + ((prow * 128 + pcol * 2) ^ ((prow & 7) << 4))) =
                        __float2bfloat16(s[nt][r]);
                }
            #pragma unroll
            for (int kk = 0; kk < 2; ++kk) {
                const int pr = lane & 15;
                short8 pf = *(const short8*)((const char*)Psm[wave] + pr * 128 +
                            ((kk * 64 + (lane >> 4) * 16) ^ ((pr & 7) << 4)));
                __builtin_amdgcn_s_setprio(1);
                #pragma unroll
                for (int j = 0; j < 8; ++j) {
                    const int rb = j * 16 + (lane & 15);
                    short8 vf = *(const short8*)((const char*)Vs + rb * 128 +
                                ((kk * 64 + (lane >> 4) * 16) ^ ((rb & 7) << 4)));
                    oacc[j] = __builtin_amdgcn_mfma_f32_16x16x32_bf16(pf, vf, oacc[j], 0, 0, 0);
                }
                __builtin_amdgcn_s_setprio(0);
            }
            cur ^= 1;
        }
        __syncthreads();   // protect LDS buffers before next pass restages

        #pragma unroll
        for (int r = 0; r < 4; ++r) {
            const float inv = 1.0f / l_run[r];
            const int qrow = qt * 64 + wave * 16 + (lane >> 4) * 4 + r;
            bf16* dst = AO + (size_t)(b * Tt + qrow) * 2048 + h * 128 + (lane & 15);
            #pragma unroll
            for (int j = 0; j < 8; ++j)
                dst[j * 16] = __float2bfloat16(oacc[j][r] * inv);
        }
    }
}

extern "C" void kernel_launch(void* const* d_in, const int* in_sizes, int n_in,
                              void* d_out, int out_size, void* d_ws, size_t ws_size,
                              hipStream_t stream) {
    const float* x    = (const float*)d_in[0];
    const float* cosT = (const float*)d_in[2];
    const float* sinT = (const float*)d_in[3];
    const float* Wq   = (const float*)d_in[4];
    const float* Wk   = (const float*)d_in[5];
    const float* Wv   = (const float*)d_in[6];
    const float* Wo   = (const float*)d_in[7];
    const float* qs   = (const float*)d_in[8];
    const float* ks   = (const float*)d_in[9];

    char* ws = (char*)d_ws;
    bf16* xb   = (bf16*)(ws);                    // 16.78 MB
    bf16* Wcat = (bf16*)(ws + 16777216);         // [3072][2048] 12.58 MB
    bf16* Wot  = (bf16*)(ws + 29360128);         // [2048][2048] 8.39 MB
    bf16* QKV  = (bf16*)(ws + 37748736);         // [4096][3072] 25.17 MB
    bf16* Qr   = (bf16*)(ws + 62914560);         // [B][H][T][D] 16.78 MB
    bf16* Kr   = (bf16*)(ws + 79691776);         // [B][G][T][D] 4.19 MB
    bf16* Vtp  = (bf16*)(ws + 83886080);         // [B][G][D][T] 4.19 MB
    bf16* AO   = (bf16*)(ws + 88080384);         // [B*T][H*D]  16.78 MB

    k_cast_bf16<<<8192, 256, 0, stream>>>(x, xb, 2097152);
    dim3 tb(32, 8);
    k_cast_transpose<<<dim3(64, 64), tb, 0, stream>>>(Wq, Wcat, 2048, 2048, 2048);
    k_cast_transpose<<<dim3(16, 64), tb, 0, stream>>>(Wk, Wcat + (size_t)2048 * 2048, 2048, 512, 2048);
    k_cast_transpose<<<dim3(16, 64), tb, 0, stream>>>(Wv, Wcat + (size_t)2560 * 2048, 2048, 512, 2048);
    k_cast_transpose<<<dim3(64, 64), tb, 0, stream>>>(Wo, Wot, 2048, 2048, 2048);

    k_gemm_bt<0><<<dim3(24, 32), 256, 0, stream>>>(xb, Wcat, QKV, 4096, 3072, 2048);
    k_qkv_post<<<4096, 256, 0, stream>>>(QKV, cosT, sinT, qs, ks, Qr, Kr);
    k_vt<<<dim3(2, 32, 8), dim3(64, 8), 0, stream>>>(QKV, Vtp);
    k_attn<<<512, 256, 0, stream>>>(Qr, Kr, Vtp, AO);
    k_gemm_bt<1><<<dim3(16, 32), 256, 0, stream>>>(AO, Wot, d_out, 4096, 2048, 2048);
}

// Round 4
// 199.254 us; speedup vs baseline: 1.7675x; 1.1324x over previous
//
#include <hip/hip_runtime.h>
#include <hip/hip_bf16.h>

#define Bq 2
#define Tt 2048
#define Cc 2048
#define Hh 16
#define Dd 128
#define Gg 4

using bf16 = __hip_bfloat16;
typedef __attribute__((ext_vector_type(8))) short short8;
typedef __attribute__((ext_vector_type(4))) float f32x4;

__device__ __forceinline__ void gload_lds16(const void* g, void* l) {
    __builtin_amdgcn_global_load_lds(
        (const __attribute__((address_space(1))) unsigned int*)g,
        (__attribute__((address_space(3))) unsigned int*)l, 16, 0, 0);
}

// ---------------- cast x (f32 -> bf16), 4 elems/thread ----------------
__global__ void k_cast_bf16(const float* __restrict__ in, bf16* __restrict__ out, int n4) {
    int i = blockIdx.x * blockDim.x + threadIdx.x;
    if (i >= n4) return;
    float4 v = ((const float4*)in)[i];
    union { bf16 h[4]; uint2 u; } u;
    u.h[0] = __float2bfloat16(v.x);
    u.h[1] = __float2bfloat16(v.y);
    u.h[2] = __float2bfloat16(v.z);
    u.h[3] = __float2bfloat16(v.w);
    ((uint2*)out)[i] = u.u;
}

// ---------------- cast + transpose: in[rows][cols] f32 -> out[cols][ostride] bf16 ----------------
__global__ void k_cast_transpose(const float* __restrict__ in, bf16* __restrict__ out,
                                 int rows, int cols, int ostride) {
    __shared__ float tile[32][33];
    int c0 = blockIdx.x * 32, r0 = blockIdx.y * 32;
    int tx = threadIdx.x, ty = threadIdx.y;  // block (32,8)
    #pragma unroll
    for (int k = 0; k < 4; ++k)
        tile[ty + 8*k][tx] = in[(size_t)(r0 + ty + 8*k) * cols + c0 + tx];
    __syncthreads();
    #pragma unroll
    for (int k = 0; k < 4; ++k)
        out[(size_t)(c0 + ty + 8*k) * ostride + r0 + tx] = __float2bfloat16(tile[tx][ty + 8*k]);
}

// ---------------- bf16 transpose of V columns of QKV -> Vt[b][g][d][t] ----------------
__global__ void k_vt(const bf16* __restrict__ QKV, bf16* __restrict__ Vt) {
    __shared__ bf16 tile[64][65];
    const int d0 = blockIdx.x * 64, t0 = blockIdx.y * 64;
    const int bg = blockIdx.z;
    const int b = bg >> 2, g = bg & 3;
    const int tx = threadIdx.x, ty = threadIdx.y;
    const bf16* src = QKV + (size_t)(b * Tt) * 3072 + 2560 + g * 128;
    #pragma unroll
    for (int k = 0; k < 8; ++k)
        tile[ty + 8*k][tx] = src[(size_t)(t0 + ty + 8*k) * 3072 + d0 + tx];
    __syncthreads();
    bf16* dst = Vt + (size_t)bg * Dd * Tt;
    #pragma unroll
    for (int k = 0; k < 8; ++k)
        dst[(size_t)(d0 + ty + 8*k) * Tt + t0 + tx] = tile[tx][ty + 8*k];
}

// ---------------- GEMM: C[M][N] = A[M][K] @ Bt[N][K]^T, bf16 in, f32 acc ----------------
template<int OUTF32>
__global__ __launch_bounds__(256)
void k_gemm_bt(const bf16* __restrict__ A, const bf16* __restrict__ Bt,
               void* __restrict__ C, int M, int N, int K) {
    __shared__ __align__(16) bf16 As[128 * 64];
    __shared__ __align__(16) bf16 Bs[128 * 64];
    const int lane = threadIdx.x & 63;
    const int wave = threadIdx.x >> 6;
    const int row0 = blockIdx.y * 128;
    const int col0 = blockIdx.x * 128;
    const int wm = wave >> 1, wn = wave & 1;
    f32x4 acc[4][4] = {};

    const int srow = lane >> 3;
    const int schunk = ((lane & 7) ^ srow) * 8;

    for (int k0 = 0; k0 < K; k0 += 64) {
        #pragma unroll
        for (int j = 0; j < 4; ++j) {
            const int c = j * 4 + wave;
            const int rt = c * 8 + srow;
            gload_lds16(A  + (size_t)(row0 + rt) * K + k0 + schunk, As + c * 512);
            gload_lds16(Bt + (size_t)(col0 + rt) * K + k0 + schunk, Bs + c * 512);
        }
        __syncthreads();
        #pragma unroll
        for (int kk = 0; kk < 2; ++kk) {
            short8 af[4], bfr[4];
            #pragma unroll
            for (int i = 0; i < 4; ++i) {
                const int ra = wm * 64 + i * 16 + (lane & 15);
                af[i] = *(const short8*)((const char*)As + ra * 128 +
                        ((kk * 64 + (lane >> 4) * 16) ^ ((ra & 7) << 4)));
                const int rb = wn * 64 + i * 16 + (lane & 15);
                bfr[i] = *(const short8*)((const char*)Bs + rb * 128 +
                        ((kk * 64 + (lane >> 4) * 16) ^ ((rb & 7) << 4)));
            }
            __builtin_amdgcn_s_setprio(1);
            #pragma unroll
            for (int i = 0; i < 4; ++i)
                #pragma unroll
                for (int j = 0; j < 4; ++j)
                    acc[i][j] = __builtin_amdgcn_mfma_f32_16x16x32_bf16(af[i], bfr[j], acc[i][j], 0, 0, 0);
            __builtin_amdgcn_s_setprio(0);
        }
        __syncthreads();
    }

    const int crow0 = row0 + wm * 64 + (lane >> 4) * 4;
    const int ccol0 = col0 + wn * 64 + (lane & 15);
    #pragma unroll
    for (int i = 0; i < 4; ++i)
        #pragma unroll
        for (int j = 0; j < 4; ++j)
            #pragma unroll
            for (int r = 0; r < 4; ++r) {
                const size_t idx = (size_t)(crow0 + i * 16 + r) * N + ccol0 + j * 16;
                const float v = acc[i][j][r];
                if (OUTF32) ((float*)C)[idx] = v;
                else        ((bf16*)C)[idx] = __float2bfloat16(v);
            }
}

// ---------------- RMSNorm + RoPE + scatter Q,K; Q pre-scaled by D^-1/2 ----------------
__global__ void k_qkv_post(const bf16* __restrict__ QKV,
                           const float* __restrict__ cosT, const float* __restrict__ sinT,
                           const float* __restrict__ qs, const float* __restrict__ ks,
                           bf16* __restrict__ Qr, bf16* __restrict__ Kr) {
    const int bt = blockIdx.x;
    const int b = bt >> 11;
    const int t = bt & 2047;
    const int lane = threadIdx.x & 63;
    const int wave = threadIdx.x >> 6;
    const float c1 = cosT[t * 128 + lane],      c2 = cosT[t * 128 + 64 + lane];
    const float s1 = sinT[t * 128 + lane],      s2 = sinT[t * 128 + 64 + lane];
    const float qs1 = qs[lane], qs2 = qs[lane + 64];
    const float ks1 = ks[lane], ks2 = ks[lane + 64];
    const bf16* rowb = QKV + (size_t)bt * 3072;
    for (int rr = wave; rr < 20; rr += 4) {
        const bf16* src = rowb + rr * 128;
        const float x1 = __bfloat162float(src[lane]);
        const float x2 = __bfloat162float(src[lane + 64]);
        bf16* dst;
        if (rr < 16) dst = Qr + ((size_t)(b * Hh + rr) * Tt + t) * 128;
        else         dst = Kr + ((size_t)(b * Gg + (rr - 16)) * Tt + t) * 128;
        float ssum = x1 * x1 + x2 * x2;
        #pragma unroll
        for (int o = 32; o > 0; o >>= 1) ssum += __shfl_xor(ssum, o);
        const float inv = rsqrtf(ssum * (1.0f / 128.0f) + 1e-6f);
        const float post = (rr < 16) ? 0.08838834764831845f : 1.0f;  // fold 1/sqrt(D) into Q
        const float sc1 = ((rr < 16) ? qs1 : ks1) * inv;
        const float sc2 = ((rr < 16) ? qs2 : ks2) * inv;
        const float y1 = x1 * sc1;
        const float y2 = x2 * sc2;
        dst[lane]      = __float2bfloat16((y1 * c1 - y2 * s1) * post);
        dst[lane + 64] = __float2bfloat16((y2 * c2 + y1 * s2) * post);
    }
}

// ---------------- causal flash attention, GQA, fold-paired, double-buffered ----------------
// No running-max: RMSNorm'd Q,K give |S| <= sqrt(128) (Cauchy-Schwarz), so exp(S) is
// f32/bf16-safe with m=0. l is a per-lane partial, reduced once at pass end.
__global__ __launch_bounds__(256)
void k_attn(const bf16* __restrict__ Qr, const bf16* __restrict__ Kr,
            const bf16* __restrict__ Vt, bf16* __restrict__ AO) {
    __shared__ __align__(16) bf16 Ksm[2][64 * 128];
    __shared__ __align__(16) bf16 Vsm[2][128 * 64];
    __shared__ __align__(16) bf16 Psm[4][16 * 64];
    const int id = blockIdx.x;
    const int bg = id & 7;            // one (b,g) per XCD -> K/V L2-resident
    const int wid = id >> 3;          // 0..63
    const int pair = wid & 15;
    const int hg = wid >> 4;          // 0..3
    const int b = bg >> 2, g = bg & 3;
    const int h = g * 4 + hg;
    const int lane = threadIdx.x & 63;
    const int wave = threadIdx.x >> 6;

    const bf16* Kbase = Kr + (size_t)(b * Gg + g) * Tt * Dd;
    const bf16* Vbase = Vt + (size_t)(b * Gg + g) * Dd * Tt;

    for (int pass = 0; pass < 2; ++pass) {
        const int qt = pass ? (31 - pair) : pair;
        const bf16* Qbase = Qr + ((size_t)(b * Hh + h) * Tt + qt * 64) * Dd;

        short8 qf[4];
        #pragma unroll
        for (int kk = 0; kk < 4; ++kk)
            qf[kk] = *(const short8*)(Qbase + (size_t)(wave * 16 + (lane & 15)) * 128 + kk * 32 + (lane >> 4) * 8);

        float l_run[4] = {0.f, 0.f, 0.f, 0.f};   // per-lane partial row-sums
        f32x4 oacc[8];
        #pragma unroll
        for (int j = 0; j < 8; ++j) oacc[j] = (f32x4){0.f, 0.f, 0.f, 0.f};

        // stage tile 0 into buffer 0
        {
            #pragma unroll
            for (int j = 0; j < 4; ++j) {
                const int c = j * 4 + wave;
                const int rtk = c * 4 + (lane >> 4);
                const int chk = (lane & 15) ^ (rtk & 7);
                gload_lds16(Kbase + (size_t)rtk * 128 + chk * 8, Ksm[0] + c * 512);
                const int rtv = c * 8 + (lane >> 3);
                const int chv = (lane & 7) ^ ((lane >> 3) & 7);
                gload_lds16(Vbase + (size_t)rtv * Tt + chv * 8, Vsm[0] + c * 512);
            }
        }

        int cur = 0;
        for (int tk = 0; tk <= qt; ++tk) {
            __syncthreads();   // buf[cur] staged (barrier drains vmcnt)

            if (tk < qt) {     // prefetch next tile into other buffer; hides under compute
                const int k0n = (tk + 1) * 64;
                #pragma unroll
                for (int j = 0; j < 4; ++j) {
                    const int c = j * 4 + wave;
                    const int rtk = c * 4 + (lane >> 4);
                    const int chk = (lane & 15) ^ (rtk & 7);
                    gload_lds16(Kbase + (size_t)(k0n + rtk) * 128 + chk * 8, Ksm[cur ^ 1] + c * 512);
                    const int rtv = c * 8 + (lane >> 3);
                    const int chv = (lane & 7) ^ ((lane >> 3) & 7);
                    gload_lds16(Vbase + (size_t)rtv * Tt + k0n + chv * 8, Vsm[cur ^ 1] + c * 512);
                }
            }

            const bf16* Ks = Ksm[cur];
            const bf16* Vs = Vsm[cur];

            f32x4 s[4];
            #pragma unroll
            for (int nt = 0; nt < 4; ++nt) s[nt] = (f32x4){0.f, 0.f, 0.f, 0.f};
            __builtin_amdgcn_s_setprio(1);
            #pragma unroll
            for (int nt = 0; nt < 4; ++nt) {
                #pragma unroll
                for (int kk = 0; kk < 4; ++kk) {
                    const int rk = nt * 16 + (lane & 15);
                    short8 kf = *(const short8*)((const char*)Ks + rk * 256 +
                                ((kk * 64 + (lane >> 4) * 16) ^ ((rk & 7) << 4)));
                    s[nt] = __builtin_amdgcn_mfma_f32_16x16x32_bf16(qf[kk], kf, s[nt], 0, 0, 0);
                }
            }
            __builtin_amdgcn_s_setprio(0);

            if (tk == qt) {    // mask only the diagonal tile
                const int qrow = qt * 64 + wave * 16 + (lane >> 4) * 4;
                const int k0 = tk * 64;
                #pragma unroll
                for (int nt = 0; nt < 4; ++nt) {
                    const int kcol = k0 + nt * 16 + (lane & 15);
                    #pragma unroll
                    for (int r = 0; r < 4; ++r)
                        if (kcol > qrow + r) s[nt][r] = -1e30f;
                }
            }

            // fixed m=0 softmax numerator: p = exp(s); per-lane partial sums only
            #pragma unroll
            for (int nt = 0; nt < 4; ++nt)
                #pragma unroll
                for (int r = 0; r < 4; ++r) {
                    const float p = __expf(s[nt][r]);
                    l_run[r] += p;
                    s[nt][r] = p;
                }

            #pragma unroll
            for (int nt = 0; nt < 4; ++nt)
                #pragma unroll
                for (int r = 0; r < 4; ++r) {
                    const int prow = (lane >> 4) * 4 + r;
                    const int pcol = nt * 16 + (lane & 15);
                    *(bf16*)((char*)Psm[wave] + ((prow * 128 + pcol * 2) ^ ((prow & 7) << 4))) =
                        __float2bfloat16(s[nt][r]);
                }
            #pragma unroll
            for (int kk = 0; kk < 2; ++kk) {
                const int pr = lane & 15;
                short8 pf = *(const short8*)((const char*)Psm[wave] + pr * 128 +
                            ((kk * 64 + (lane >> 4) * 16) ^ ((pr & 7) << 4)));
                __builtin_amdgcn_s_setprio(1);
                #pragma unroll
                for (int j = 0; j < 8; ++j) {
                    const int rb = j * 16 + (lane & 15);
                    short8 vf = *(const short8*)((const char*)Vs + rb * 128 +
                                ((kk * 64 + (lane >> 4) * 16) ^ ((rb & 7) << 4)));
                    oacc[j] = __builtin_amdgcn_mfma_f32_16x16x32_bf16(pf, vf, oacc[j], 0, 0, 0);
                }
                __builtin_amdgcn_s_setprio(0);
            }
            cur ^= 1;
        }
        __syncthreads();   // protect LDS buffers before next pass restages

        // one cross-lane reduce per pass: sum partials over the 16 lanes sharing a q-row
        #pragma unroll
        for (int o = 1; o < 16; o <<= 1)
            #pragma unroll
            for (int r = 0; r < 4; ++r) l_run[r] += __shfl_xor(l_run[r], o);

        #pragma unroll
        for (int r = 0; r < 4; ++r) {
            const float inv = 1.0f / l_run[r];
            const int qrow = qt * 64 + wave * 16 + (lane >> 4) * 4 + r;
            bf16* dst = AO + (size_t)(b * Tt + qrow) * 2048 + h * 128 + (lane & 15);
            #pragma unroll
            for (int j = 0; j < 8; ++j)
                dst[j * 16] = __float2bfloat16(oacc[j][r] * inv);
        }
    }
}

extern "C" void kernel_launch(void* const* d_in, const int* in_sizes, int n_in,
                              void* d_out, int out_size, void* d_ws, size_t ws_size,
                              hipStream_t stream) {
    const float* x    = (const float*)d_in[0];
    const float* cosT = (const float*)d_in[2];
    const float* sinT = (const float*)d_in[3];
    const float* Wq   = (const float*)d_in[4];
    const float* Wk   = (const float*)d_in[5];
    const float* Wv   = (const float*)d_in[6];
    const float* Wo   = (const float*)d_in[7];
    const float* qs   = (const float*)d_in[8];
    const float* ks   = (const float*)d_in[9];

    char* ws = (char*)d_ws;
    bf16* xb   = (bf16*)(ws);                    // 16.78 MB
    bf16* Wcat = (bf16*)(ws + 16777216);         // [3072][2048] 12.58 MB
    bf16* Wot  = (bf16*)(ws + 29360128);         // [2048][2048] 8.39 MB
    bf16* QKV  = (bf16*)(ws + 37748736);         // [4096][3072] 25.17 MB
    bf16* Qr   = (bf16*)(ws + 62914560);         // [B][H][T][D] 16.78 MB
    bf16* Kr   = (bf16*)(ws + 79691776);         // [B][G][T][D] 4.19 MB
    bf16* Vtp  = (bf16*)(ws + 83886080);         // [B][G][D][T] 4.19 MB
    bf16* AO   = (bf16*)(ws + 88080384);         // [B*T][H*D]  16.78 MB

    k_cast_bf16<<<8192, 256, 0, stream>>>(x, xb, 2097152);
    dim3 tb(32, 8);
    k_cast_transpose<<<dim3(64, 64), tb, 0, stream>>>(Wq, Wcat, 2048, 2048, 2048);
    k_cast_transpose<<<dim3(16, 64), tb, 0, stream>>>(Wk, Wcat + (size_t)2048 * 2048, 2048, 512, 2048);
    k_cast_transpose<<<dim3(16, 64), tb, 0, stream>>>(Wv, Wcat + (size_t)2560 * 2048, 2048, 512, 2048);
    k_cast_transpose<<<dim3(64, 64), tb, 0, stream>>>(Wo, Wot, 2048, 2048, 2048);

    k_gemm_bt<0><<<dim3(24, 32), 256, 0, stream>>>(xb, Wcat, QKV, 4096, 3072, 2048);
    k_qkv_post<<<4096, 256, 0, stream>>>(QKV, cosT, sinT, qs, ks, Qr, Kr);
    k_vt<<<dim3(2, 32, 8), dim3(64, 8), 0, stream>>>(QKV, Vtp);
    k_attn<<<512, 256, 0, stream>>>(Qr, Kr, Vtp, AO);
    k_gemm_bt<1><<<dim3(16, 32), 256, 0, stream>>>(AO, Wot, d_out, 4096, 2048, 2048);
}